// Round 1
// baseline (139.807 us; speedup 1.0000x reference)
//
#include <hip/hip_runtime.h>

// PolynomialAttn: B=2,H=16,S=2048,D=64, degree=2, eps=1e-4, fp32 in/out.
// v11: occupancy push. v10 was latency-bound at 2 waves/SIMD (LDS 69KB/block
// and ~216 unified regs both capped 2 blocks/CU; MfmaUtil 24% with HBM at 7%
// and L2 at ~28% of ceiling). v11 halves per-wave state: BQ 128->64, one
// 32-row strip per wave, single-buffered K/V fragment streams (issue-to-use
// distance inside the skewed body covers L2 latency via 4-wave TLP),
// epilogue LDS 69->34.5KB, __launch_bounds__(256,4) -> 4 blocks/CU,
// 16 waves/CU. Same Kf/Vf fragment layouts + prepass as v10.

#define S_LEN 2048
#define DH    64
#define BQ    64
#define BK    64
#define EPSTR 68        // epilogue fp32 stride
#define PSTR  65        // prepass V-transpose LDS stride
#define BH_N  32        // B*H
#define PER_BH (S_LEN * DH)   // 131072 elems
#define NT    (S_LEN / BK)    // 32 KV tiles

typedef __bf16 bf16x8 __attribute__((ext_vector_type(8)));
typedef __bf16 bf16x2 __attribute__((ext_vector_type(2)));
typedef float  f32x2  __attribute__((ext_vector_type(2)));
typedef float  f32x4  __attribute__((ext_vector_type(4)));
typedef float  f32x16 __attribute__((ext_vector_type(16)));
typedef unsigned int uivec2 __attribute__((ext_vector_type(2)));

__device__ __forceinline__ unsigned short f2bf(float f) {
    union { float f; unsigned int u; } x; x.f = f;
    unsigned int u = x.u;
    return (unsigned short)((u + 0x7fffu + ((u >> 16) & 1u)) >> 16);  // RNE
}

__device__ __forceinline__ unsigned int pack2bf(float lo, float hi) {
#if __has_builtin(__builtin_amdgcn_cvt_pk_bf16_f32)
    bf16x2 p = __builtin_amdgcn_cvt_pk_bf16_f32(lo, hi);
    union { bf16x2 v; unsigned int u; } c; c.v = p;
    return c.u;
#else
    return (unsigned int)f2bf(lo) | ((unsigned int)f2bf(hi) << 16);
#endif
}

__device__ __forceinline__ void pl32swap(unsigned int& a, unsigned int& b) {
#if __has_builtin(__builtin_amdgcn_permlane32_swap)
    uivec2 r = __builtin_amdgcn_permlane32_swap(a, b, false, false);
    a = r[0]; b = r[1];
#else
    asm("v_permlane32_swap_b32 %0, %1" : "+v"(a), "+v"(b));
#endif
}

// ---------------- prepass: K -> fragment-order bf16, V -> V^T fragment-order bf16 ----
// Kf layout (ushorts): [bh][t][e][ks][lane]*8 ; lane(l31,h) holds
//   K[bh][64t + 32e + l31][16ks + 8h + 0..7]
// Vf layout (ushorts): [bh][t][e][ksl][mt][lane]*8 ; lane(l31,h) holds
//   V^T[bh][mt*32 + l31][64t + 32e + 16ksl + 8h + 0..7]
__global__ __launch_bounds__(256)
void prepass_kernel(const float* __restrict__ kg, const float* __restrict__ vg,
                    unsigned short* __restrict__ kfo, unsigned short* __restrict__ vfo)
{
    __shared__ unsigned short Lk[64 * 72];
    __shared__ unsigned short Lv[64 * PSTR];
    const int tid = threadIdx.x;
    const int bh  = blockIdx.y;
    const int t   = blockIdx.x;
    const size_t base = (size_t)bh * PER_BH + (size_t)t * 64 * DH;

    const float4* kf4 = (const float4*)(kg + base);
    const float4* vf4 = (const float4*)(vg + base);
    #pragma unroll
    for (int r = 0; r < 4; ++r) {
        int idx = r * 256 + tid;              // float4 index in 64x64 tile
        int row = idx >> 4, c4 = idx & 15;
        float4 f = kf4[idx];
        ushort4 hh;
        hh.x = f2bf(f.x); hh.y = f2bf(f.y); hh.z = f2bf(f.z); hh.w = f2bf(f.w);
        *(ushort4*)&Lk[row * 72 + c4 * 4] = hh;
        float4 g = vf4[idx];
        unsigned short* pv = &Lv[row * PSTR + c4 * 4];
        pv[0] = f2bf(g.x); pv[1] = f2bf(g.y); pv[2] = f2bf(g.z); pv[3] = f2bf(g.w);
    }
    __syncthreads();

    unsigned short* kout = kfo + (size_t)bh * PER_BH + (size_t)t * 4096;
    #pragma unroll
    for (int r = 0; r < 2; ++r) {
        int pos = r * 256 + tid;
        int lam = pos & 63, rest = pos >> 6;
        int e = rest >> 2, ks = rest & 3;
        int l31 = lam & 31, h = lam >> 5;
        uint4 v = *(const uint4*)&Lk[(e * 32 + l31) * 72 + ks * 16 + h * 8];
        *(uint4*)(kout + (size_t)pos * 8) = v;
    }
    unsigned short* vout = vfo + (size_t)bh * PER_BH + (size_t)t * 4096;
    #pragma unroll
    for (int r = 0; r < 2; ++r) {
        int pos = r * 256 + tid;
        int lam = pos & 63, rest = pos >> 6;
        int e = rest >> 2, ksl = (rest >> 1) & 1, mt = rest & 1;
        int l31 = lam & 31, h = lam >> 5;
        int d  = mt * 32 + l31;
        int j0 = e * 32 + ksl * 16 + h * 8;
        union { unsigned short s[8]; uint4 u; } u;
        #pragma unroll
        for (int jj = 0; jj < 8; ++jj) u.s[jj] = Lv[(j0 + jj) * PSTR + d];
        *(uint4*)(vout + (size_t)pos * 8) = u.u;
    }
}

// ---------------- main kernel: 4 blocks/CU, skewed QK/PV, single-buffer streams ------
__global__ __launch_bounds__(256, 4)
void poly_attn_main(const float* __restrict__ qg,
                    const unsigned short* __restrict__ kfo,
                    const unsigned short* __restrict__ vfo,
                    float* __restrict__ og)
{
    __shared__ float epb[4 * 32 * EPSTR];   // one region per wave: O^T partials
    __shared__ float dbuf[128];             // per-wave denominator partials

    const int tid  = threadIdx.x;
    const int lane = tid & 63;
    const int w    = tid >> 6;
    const int sp   = w >> 1;      // strip: Q rows [32sp, 32sp+32)
    const int e    = w & 1;       // j-half of each KV tile
    const int l31  = lane & 31;
    const int h    = lane >> 5;

    // XCD swizzle: id%8 -> XCD; 4 bh per XCD (K+V 2MB working set in its L2)
    const int id = blockIdx.x;
    const int r5 = id & 31;
    const int bh = (r5 & 7) * 4 + (r5 >> 3);
    const int qt = id >> 5;                 // 0..31
    const int q0 = qt * BQ;

    const float* qb = qg + ((size_t)bh * S_LEN + q0) * DH;
    const unsigned short* kw = kfo + (size_t)bh * PER_BH + e * 2048 + (size_t)lane * 8;
    const unsigned short* vw = vfo + (size_t)bh * PER_BH + e * 2048 + (size_t)lane * 8;
    float* ob = og + ((size_t)bh * S_LEN + q0) * DH;

    // ---- Q B-fragments: rows 32sp + l31, cols 16ks + 8h + 0..7 ----
    bf16x8 qfrag[4];
    #pragma unroll
    for (int ks = 0; ks < 4; ++ks) {
        const float* qp = qb + (32 * sp + l31) * DH + ks * 16 + h * 8;
        float4 f0 = *(const float4*)qp;
        float4 f1 = *(const float4*)(qp + 4);
        union { unsigned int d[4]; bf16x8 v; } u;
        u.d[0] = pack2bf(f0.x, f0.y);
        u.d[1] = pack2bf(f0.z, f0.w);
        u.d[2] = pack2bf(f1.x, f1.y);
        u.d[3] = pack2bf(f1.z, f1.w);
        qfrag[ks] = u.v;
    }

    f32x16 oacc[2];   // [mt]: O^T[d=mt*32+(r&3)+8(r>>2)+4h][i=l31] j-half partial
    #pragma unroll
    for (int mt = 0; mt < 2; ++mt)
        #pragma unroll
        for (int r = 0; r < 16; ++r) oacc[mt][r] = 0.f;
    f32x2 ds2; ds2[0] = 0.f; ds2[1] = 0.f;

    uint4 kbuf[4], vbuf[4];
    unsigned int bsave[2][4];   // [ksl][dword] transformed B-frags (skew carry)

    const unsigned short* kload = kw;
    const unsigned short* vload = vw;
    #pragma unroll
    for (int x = 0; x < 4; ++x) kbuf[x] = *(const uint4*)(kload + x * 512);
    kload += 4096;

#define KLOAD()                                                                     \
        { _Pragma("unroll")                                                         \
          for (int x = 0; x < 4; ++x) kbuf[x] = *(const uint4*)(kload + x * 512);   \
          kload += 4096; }

#define VLOAD()                                                                     \
        { _Pragma("unroll")                                                         \
          for (int x = 0; x < 4; ++x) vbuf[x] = *(const uint4*)(vload + x * 512);   \
          vload += 4096; }

#define QK_STAGE()                                                                  \
        f32x16 acc;                                                                 \
        _Pragma("unroll")                                                           \
        for (int r = 0; r < 16; ++r) acc[r] = 0.f;                                  \
        _Pragma("unroll")                                                           \
        for (int ks = 0; ks < 4; ++ks) {                                            \
            union { uint4 u; bf16x8 v; } kc; kc.u = kbuf[ks];                       \
            acc = __builtin_amdgcn_mfma_f32_32x32x16_bf16(kc.v, qfrag[ks], acc, 0, 0, 0); \
        }

#define PV_STAGE()                                                                  \
        _Pragma("unroll")                                                           \
        for (int ksl = 0; ksl < 2; ++ksl) {                                         \
            union { unsigned int d[4]; bf16x8 v; } bu;                              \
            bu.d[0] = bsave[ksl][0]; bu.d[1] = bsave[ksl][1];                       \
            bu.d[2] = bsave[ksl][2]; bu.d[3] = bsave[ksl][3];                       \
            _Pragma("unroll")                                                       \
            for (int mt = 0; mt < 2; ++mt) {                                        \
                union { uint4 u; bf16x8 v; } vv; vv.u = vbuf[ksl * 2 + mt];         \
                oacc[mt] = __builtin_amdgcn_mfma_f32_32x32x16_bf16(vv.v, bu.v, oacc[mt], 0, 0, 0); \
            }                                                                       \
        }

#define XF_STAGE()                                                                  \
        _Pragma("unroll")                                                           \
        for (int ksl = 0; ksl < 2; ++ksl) {                                         \
            f32x2 va, vb, vc, vd;                                                   \
            va[0] = acc[8*ksl+0]; va[1] = acc[8*ksl+1];                             \
            vb[0] = acc[8*ksl+2]; vb[1] = acc[8*ksl+3];                             \
            vc[0] = acc[8*ksl+4]; vc[1] = acc[8*ksl+5];                             \
            vd[0] = acc[8*ksl+6]; vd[1] = acc[8*ksl+7];                             \
            va = va * va; vb = vb * vb; vc = vc * vc; vd = vd * vd;                 \
            ds2 += va; ds2 += vb; ds2 += vc; ds2 += vd;                             \
            unsigned int a0 = pack2bf(va[0], va[1]);                                \
            unsigned int a1 = pack2bf(vb[0], vb[1]);                                \
            unsigned int b0 = pack2bf(vc[0], vc[1]);                                \
            unsigned int b1 = pack2bf(vd[0], vd[1]);                                \
            pl32swap(a0, b0);                                                       \
            pl32swap(a1, b1);                                                       \
            bsave[ksl][0] = a0; bsave[ksl][1] = a1;                                 \
            bsave[ksl][2] = b0; bsave[ksl][3] = b1;                                 \
        }

    // ---- prologue: QK(0); issue k(1); transform(0) ----
    { QK_STAGE(); KLOAD(); XF_STAGE(); }

    // body T: load v(T-1); QK(T); issue k(T+1); PV(T-1); transform(T)
    for (int T = 1; T < NT - 1; ++T) {
        VLOAD();
        QK_STAGE();
        KLOAD();
        PV_STAGE();
        XF_STAGE();
    }
    // T = NT-1: no k prefetch
    { VLOAD(); QK_STAGE(); PV_STAGE(); XF_STAGE(); }
    // drain: PV(NT-1)
    { VLOAD(); PV_STAGE(); }
#undef KLOAD
#undef VLOAD
#undef QK_STAGE
#undef PV_STAGE
#undef XF_STAGE

    // ---- denominator partial (column i = l31, this wave's j-half) ----
    float wavetot;
    { float t = ds2[0] + ds2[1]; wavetot = t + __shfl_xor(t, 32); }

    // ---- epilogue: stash partials, combine wave-pair j-halves, store ----
    {
        float* ep = epb + (size_t)w * (32 * EPSTR);
        #pragma unroll
        for (int mt = 0; mt < 2; ++mt) {
            #pragma unroll
            for (int g = 0; g < 4; ++g) {
                f32x4 vv;
                vv[0] = oacc[mt][4*g+0];
                vv[1] = oacc[mt][4*g+1];
                vv[2] = oacc[mt][4*g+2];
                vv[3] = oacc[mt][4*g+3];
                // O[i=l31][d = mt*32 + 8g + 4h + 0..3]
                *(f32x4*)&ep[l31 * EPSTR + mt * 32 + 8 * g + 4 * h] = vv;
            }
        }
        if (h == 0) dbuf[w * 32 + l31] = wavetot;
    }
    __syncthreads();

    // wave w: output strip so = w>>1 (rows [32so,32so+32)), d-half ho = w&1
    const int so = w >> 1, ho = w & 1;
    const int lr = lane >> 1;
    const float den = dbuf[(2 * so + 0) * 32 + lr] + dbuf[(2 * so + 1) * 32 + lr];
    const float inv = 1.0f / fmaxf(den, 1e-4f);
    const float* ea = epb + (size_t)(2 * so + 0) * (32 * EPSTR) + lr * EPSTR;
    const float* eb = epb + (size_t)(2 * so + 1) * (32 * EPSTR) + lr * EPSTR;
    #pragma unroll
    for (int it = 0; it < 4; ++it) {
        int d0 = ho * 32 + (lane & 1) * 16 + it * 4;
        f32x4 a = *(const f32x4*)&ea[d0];
        f32x4 b = *(const f32x4*)&eb[d0];
        f32x4 sm;
        sm[0] = (a[0] + b[0]) * inv;
        sm[1] = (a[1] + b[1]) * inv;
        sm[2] = (a[2] + b[2]) * inv;
        sm[3] = (a[3] + b[3]) * inv;
        *(f32x4*)&ob[(32 * so + lr) * DH + d0] = sm;
    }
}

// ---------------- fallback (self-contained, used if ws too small) ----------------
#define LSTR 72
__global__ __launch_bounds__(256, 2)
void poly_attn_fallback(const float* __restrict__ qg, const float* __restrict__ kg,
                        const float* __restrict__ vg, float* __restrict__ og)
{
    __shared__ unsigned short Qs[64 * LSTR];
    __shared__ unsigned short Ksl[64 * LSTR];
    __shared__ unsigned short Vt[64 * LSTR];
    __shared__ unsigned short Xsl[64 * LSTR];

    const int tid  = threadIdx.x;
    const int lane = tid & 63;
    const int w    = tid >> 6;
    const int c    = lane & 15;
    const int quad = lane >> 4;
    const int i0   = w * 16;

    const int bh = blockIdx.y;
    const int q0 = blockIdx.x * 64;

    const float* qb = qg + ((size_t)bh * S_LEN + q0) * DH;
    const float* kb = kg + (size_t)bh * S_LEN * DH;
    const float* vb = vg + (size_t)bh * S_LEN * DH;
    float*       ob = og + ((size_t)bh * S_LEN + q0) * DH;

    {
        const float4* qf4 = (const float4*)qb;
        #pragma unroll
        for (int r = 0; r < 4; ++r) {
            int idx = r * 256 + tid;
            int row = idx >> 4, c4 = idx & 15;
            float4 f = qf4[idx];
            ushort4 hh;
            hh.x = f2bf(f.x); hh.y = f2bf(f.y); hh.z = f2bf(f.z); hh.w = f2bf(f.w);
            *(ushort4*)&Qs[row * LSTR + c4 * 4] = hh;
        }
    }

    f32x4 oacc[4];
    #pragma unroll
    for (int t = 0; t < 4; ++t) { oacc[t][0]=0.f; oacc[t][1]=0.f; oacc[t][2]=0.f; oacc[t][3]=0.f; }
    float dsum[4] = {0.f, 0.f, 0.f, 0.f};

    for (int t0 = 0; t0 < S_LEN; t0 += 64) {
        __syncthreads();
        {
            const float4* kf4 = (const float4*)(kb + (size_t)t0 * DH);
            const float4* vf4 = (const float4*)(vb + (size_t)t0 * DH);
            #pragma unroll
            for (int r = 0; r < 4; ++r) {
                int idx = r * 256 + tid;
                int row = idx >> 4, c4 = idx & 15;
                float4 f = kf4[idx];
                ushort4 hh;
                hh.x = f2bf(f.x); hh.y = f2bf(f.y); hh.z = f2bf(f.z); hh.w = f2bf(f.w);
                *(ushort4*)&Ksl[row * LSTR + c4 * 4] = hh;
                float4 g = vf4[idx];
                int d0 = c4 * 4;
                Vt[(d0 + 0) * LSTR + row] = f2bf(g.x);
                Vt[(d0 + 1) * LSTR + row] = f2bf(g.y);
                Vt[(d0 + 2) * LSTR + row] = f2bf(g.z);
                Vt[(d0 + 3) * LSTR + row] = f2bf(g.w);
            }
        }
        __syncthreads();

        f32x4 xacc[4];
        #pragma unroll
        for (int t = 0; t < 4; ++t) { xacc[t][0]=0.f; xacc[t][1]=0.f; xacc[t][2]=0.f; xacc[t][3]=0.f; }
        #pragma unroll
        for (int k0 = 0; k0 < 64; k0 += 32) {
            bf16x8 af = *(const bf16x8*)&Qs[(i0 + c) * LSTR + k0 + quad * 8];
            #pragma unroll
            for (int tn = 0; tn < 4; ++tn) {
                bf16x8 bfg = *(const bf16x8*)&Ksl[(tn * 16 + c) * LSTR + k0 + quad * 8];
                xacc[tn] = __builtin_amdgcn_mfma_f32_16x16x32_bf16(af, bfg, xacc[tn], 0, 0, 0);
            }
        }
        #pragma unroll
        for (int tn = 0; tn < 4; ++tn)
            #pragma unroll
            for (int r = 0; r < 4; ++r) {
                float xv = xacc[tn][r];
                float xs = xv * xv;
                dsum[r] += xs;
                Xsl[(i0 + quad * 4 + r) * LSTR + tn * 16 + c] = f2bf(xs);
            }
        __syncthreads();

        #pragma unroll
        for (int k0 = 0; k0 < 64; k0 += 32) {
            bf16x8 af = *(const bf16x8*)&Xsl[(i0 + c) * LSTR + k0 + quad * 8];
            #pragma unroll
            for (int tn = 0; tn < 4; ++tn) {
                bf16x8 bfg = *(const bf16x8*)&Vt[(tn * 16 + c) * LSTR + k0 + quad * 8];
                oacc[tn] = __builtin_amdgcn_mfma_f32_16x16x32_bf16(af, bfg, oacc[tn], 0, 0, 0);
            }
        }
    }

    #pragma unroll
    for (int r = 0; r < 4; ++r) {
        float s = dsum[r];
        s += __shfl_xor(s, 1);
        s += __shfl_xor(s, 2);
        s += __shfl_xor(s, 4);
        s += __shfl_xor(s, 8);
        dsum[r] = 1.0f / fmaxf(s, 1e-4f);
    }
    #pragma unroll
    for (int tn = 0; tn < 4; ++tn)
        #pragma unroll
        for (int r = 0; r < 4; ++r)
            ob[(i0 + quad * 4 + r) * DH + tn * 16 + c] = oacc[tn][r] * dsum[r];
}

extern "C" void kernel_launch(void* const* d_in, const int* in_sizes, int n_in,
                              void* d_out, int out_size, void* d_ws, size_t ws_size,
                              hipStream_t stream) {
    (void)in_sizes; (void)n_in; (void)out_size;
    const float* q = (const float*)d_in[0];
    const float* k = (const float*)d_in[1];
    const float* v = (const float*)d_in[2];
    float* o = (float*)d_out;

    const size_t elems = (size_t)BH_N * PER_BH;              // 4,194,304
    const size_t need  = 2 * elems * sizeof(unsigned short); // 16.78 MB

    if (ws_size >= need) {
        unsigned short* kfo = (unsigned short*)d_ws;
        unsigned short* vfo = kfo + elems;
        prepass_kernel<<<dim3(NT, BH_N), 256, 0, stream>>>(k, v, kfo, vfo);
        poly_attn_main<<<dim3(BH_N * S_LEN / BQ), 256, 0, stream>>>(q, kfo, vfo, o);
    } else {
        poly_attn_fallback<<<dim3(S_LEN / 64, BH_N), 256, 0, stream>>>(q, k, v, o);
    }
}